// Round 11
// baseline (1199.772 us; speedup 1.0000x reference)
//
#include <hip/hip_runtime.h>

// Model dims
#define T_ 64
#define B_ 1024
#define V_ 128
#define H_ 512
#define KFC 3616   // imgfc K padded (3600 + 16 zeros); 113 k-blocks of 32

typedef short bf16x8 __attribute__((ext_vector_type(8)));
typedef short bf16x4 __attribute__((ext_vector_type(4)));
typedef float f32x4 __attribute__((ext_vector_type(4)));
typedef float f32x16 __attribute__((ext_vector_type(16)));
typedef int int4v __attribute__((ext_vector_type(4)));

#define ZERO16 ((f32x16){0.f,0.f,0.f,0.f,0.f,0.f,0.f,0.f,0.f,0.f,0.f,0.f,0.f,0.f,0.f,0.f})

__device__ __forceinline__ unsigned short f2bf(float f) {
    union { float f; unsigned int i; } v; v.f = f;
    unsigned int x = v.i;
    return (unsigned short)((x + 0x7FFFu + ((x >> 16) & 1u)) >> 16);
}
__device__ __forceinline__ float sigm(float x) { return 1.f / (1.f + __expf(-x)); }
__device__ __forceinline__ float tanh_fast(float x) {
    float ax = fabsf(x);
    float t = 1.f - 2.f / (__expf(2.f * ax) + 1.f);   // saturates to 1 on overflow
    return copysignf(t, x);
}

// ---------------- fused prep: convw (5120 blk) + convow (256 blk) + cbias (8 blk) ----------------
__global__ __launch_bounds__(256) void prep_k(const float* __restrict__ xw,
                                              const float* __restrict__ hw,
                                              unsigned short* __restrict__ wt,
                                              const float* __restrict__ ow,
                                              unsigned short* __restrict__ wo,
                                              const float* __restrict__ xh_b,
                                              const float* __restrict__ hh_b,
                                              float* __restrict__ cbias,
                                              unsigned int* __restrict__ ctr) {
    int bx = blockIdx.x, tid = threadIdx.x;
    if (bx < 5120) {                                  // Wt bf16 [2048][640]: Wt[n][k]=W[k][n]
        int i = bx * 256 + tid;
        int n = i / 640, k = i - n * 640;
        float v = (k < 128) ? xw[k * 2048 + n] : hw[(k - 128) * 2048 + n];
        wt[i] = f2bf(v);
    } else if (bx < 5376) {                           // Wo bf16 [128][512]: Wo[n][k]=out_w[k][n]
        int i = (bx - 5120) * 256 + tid;
        int n = i >> 9, k = i & 511;
        wo[i] = f2bf(ow[k * 128 + n]);
    } else {                                          // cbias + flag/slot zero
        int i = (bx - 5376) * 256 + tid;
        cbias[i] = xh_b[i] + hh_b[i];
        if (i < 576) ctr[i] = 0u;                     // flags[8][64] + slot counters [8]
    }
}

// ---------------- convert inp fp32 -> bf16, PANEL-MAJOR [T][8][1024][16] ----------------
__global__ __launch_bounds__(256) void convx_k(const float* __restrict__ x,
                                               unsigned short* __restrict__ xbf) {
    int e = blockIdx.x * 256 + threadIdx.x;          // T*B*8 = 524288
    int t = e >> 13, r = e & 8191;
    int panel = r >> 10, b = r & 1023;
    const float* ip = x + ((size_t)t * 1024 + b) * 128 + panel * 16;
    unsigned short* op = xbf + (size_t)t * 131072 + panel * 16384 + b * 16;
#pragma unroll
    for (int h = 0; h < 2; ++h) {
        float4 f0 = *(const float4*)(ip + h * 8);
        float4 f1 = *(const float4*)(ip + h * 8 + 4);
        bf16x8 o;
        o[0] = (short)f2bf(f0.x); o[1] = (short)f2bf(f0.y);
        o[2] = (short)f2bf(f0.z); o[3] = (short)f2bf(f0.w);
        o[4] = (short)f2bf(f1.x); o[5] = (short)f2bf(f1.y);
        o[6] = (short)f2bf(f1.z); o[7] = (short)f2bf(f1.w);
        *(bf16x8*)(op + h * 8) = o;
    }
}

// ---------------- imgfc_w [3600][512] f32 -> wfc2 TILE-MAJOR [113][512][32] bf16 ----------------
__global__ __launch_bounds__(256) void convfw_k(const float* __restrict__ w,
                                                unsigned short* __restrict__ wn) {
    __shared__ float ts[32][257];
    int bx = blockIdx.x;                              // 226 = 113 kb x 2 n-halves
    int kb = bx >> 1, n0 = (bx & 1) * 256;
    int tid = threadIdx.x;
#pragma unroll
    for (int r = 0; r < 32; ++r) {
        int k = kb * 32 + r;
        ts[r][tid] = (k < 3600) ? w[(size_t)k * 512 + n0 + tid] : 0.f;
    }
    __syncthreads();
    unsigned short* op = wn + (size_t)kb * 16384 + (size_t)(n0 + tid) * 32;
#pragma unroll
    for (int m = 0; m < 4; ++m) {
        bf16x8 o;
#pragma unroll
        for (int e = 0; e < 8; ++e) o[e] = (short)f2bf(ts[m * 8 + e][tid]);
        *(bf16x8*)(op + m * 8) = o;
    }
}

// ---------------- conv1 3x3 pad1 + relu + 2x2 maxpool ----------------
__global__ __launch_bounds__(256) void conv1_k(const float* __restrict__ img,
                                               const float* __restrict__ w,
                                               const float* __restrict__ bias,
                                               float* __restrict__ out) {
    int id = blockIdx.x * 256 + threadIdx.x;         // B*32*32 = 1048576
    int px = id & 31, py = (id >> 5) & 31, b = id >> 10;
    const float* ip = img + b * 4096;
    float in4[4][4];
#pragma unroll
    for (int dy = 0; dy < 4; ++dy) {
        int iy = 2 * py + dy - 1;
#pragma unroll
        for (int dx = 0; dx < 4; ++dx) {
            int ix = 2 * px + dx - 1;
            in4[dy][dx] = (iy >= 0 && iy < 64 && ix >= 0 && ix < 64) ? ip[iy * 64 + ix] : 0.f;
        }
    }
    float* op = out + b * 8192 + py * 32 + px;
#pragma unroll
    for (int oc = 0; oc < 8; ++oc) {
        float wv[9];
#pragma unroll
        for (int t = 0; t < 9; ++t) wv[t] = w[oc * 9 + t];
        float bs = bias[oc];
        float m = -3.4e38f;
#pragma unroll
        for (int sy = 0; sy < 2; ++sy)
#pragma unroll
        for (int sx = 0; sx < 2; ++sx) {
            float acc = bs;
#pragma unroll
            for (int ky = 0; ky < 3; ++ky)
#pragma unroll
            for (int kx = 0; kx < 3; ++kx)
                acc += in4[sy + ky][sx + kx] * wv[ky * 3 + kx];
            m = fmaxf(m, acc);
        }
        op[oc * 1024] = fmaxf(m, 0.f);
    }
}

// ---------------- conv2 5x5 pad1 + relu + 2x2 maxpool -> feat2 TILE-MAJOR [113][1024][32] ----------------
__device__ __forceinline__ int c2idx(int ic, int y, int x) {
    return ((ic * 34 + y) * 2 + (x & 1)) * 18 + (x >> 1);
}
__global__ __launch_bounds__(256) void conv2_k(const float* __restrict__ in,
                                               const float* __restrict__ w,
                                               const float* __restrict__ bias,
                                               unsigned short* __restrict__ feat) {
    __shared__ float in_s[8 * 34 * 36];
    __shared__ float w_s[3200];
    __shared__ float b_s[16];
    int tid = threadIdx.x, b = blockIdx.x;
    for (int e = tid; e < 8 * 34 * 34; e += 256) {
        int ic = e / 1156, r = e - ic * 1156;
        int y = r / 34, xx = r - y * 34;
        float v = 0.f;
        if (y >= 1 && y <= 32 && xx >= 1 && xx <= 32)
            v = in[b * 8192 + ic * 1024 + (y - 1) * 32 + (xx - 1)];
        in_s[c2idx(ic, y, xx)] = v;
    }
    for (int e = tid; e < 3200; e += 256) w_s[e] = w[e];
    if (tid < 16) b_s[tid] = bias[tid];
    if (tid < 16) feat[(size_t)112 * 32768 + (size_t)b * 32 + 16 + tid] = 0;  // K tail
    __syncthreads();
    for (int o = tid; o < 3600; o += 256) {
        int oc = o / 225, p = o - oc * 225;
        int py = p / 15, px = p - py * 15;
        int y0 = 2 * py;
        float a00, a01, a10, a11;
        a00 = a01 = a10 = a11 = b_s[oc];
        for (int ic = 0; ic < 8; ++ic) {
            const float* wp = w_s + (oc * 8 + ic) * 25;
            float cur[6], nxt[6];
#pragma unroll
            for (int xx = 0; xx < 6; ++xx) cur[xx] = in_s[c2idx(ic, y0, 2 * px + xx)];
#pragma unroll
            for (int ky = 0; ky < 5; ++ky) {
#pragma unroll
                for (int xx = 0; xx < 6; ++xx) nxt[xx] = in_s[c2idx(ic, y0 + ky + 1, 2 * px + xx)];
#pragma unroll
                for (int kx = 0; kx < 5; ++kx) {
                    float wv = wp[ky * 5 + kx];
                    a00 += cur[kx    ] * wv;
                    a01 += cur[kx + 1] * wv;
                    a10 += nxt[kx    ] * wv;
                    a11 += nxt[kx + 1] * wv;
                }
#pragma unroll
                for (int xx = 0; xx < 6; ++xx) cur[xx] = nxt[xx];
            }
        }
        float mx = fmaxf(fmaxf(a00, a01), fmaxf(a10, a11));
        feat[(size_t)(o >> 5) * 32768 + (size_t)b * 32 + (o & 31)] = f2bf(fmaxf(mx, 0.f));
    }
}

#define MFMA16(a, b, c) __builtin_amdgcn_mfma_f32_16x16x32_bf16((a), (b), (c), 0, 0, 0)
#define MFMA32(a, b, c) __builtin_amdgcn_mfma_f32_32x32x16_bf16((a), (b), (c), 0, 0, 0)

// ---------------- imgfc via MFMA: e = relu(feat @ W + b), tile-major operands ----------------
__global__ __launch_bounds__(256) void imgfc_mfma(const unsigned short* __restrict__ A2,
                                                  const unsigned short* __restrict__ W2,
                                                  const float* __restrict__ bias,
                                                  float* __restrict__ E) {
    const int tid = threadIdx.x;
    const int wv = tid >> 6, lane = tid & 63;
    const int quad = lane >> 4, l16 = lane & 15;
    const int row0 = blockIdx.x * 64 + wv * 16;
    const int col0 = blockIdx.y * 32;
    const unsigned short* ap = A2 + (size_t)(row0 + l16) * 32 + quad * 8;
    const unsigned short* bp0 = W2 + (size_t)(col0 + l16) * 32 + quad * 8;
    const unsigned short* bp1 = W2 + (size_t)(col0 + 16 + l16) * 32 + quad * 8;
    f32x4 acc0 = (f32x4){0.f, 0.f, 0.f, 0.f};
    f32x4 acc1 = (f32x4){0.f, 0.f, 0.f, 0.f};
#pragma unroll 4
    for (int kb = 0; kb < 113; ++kb) {
        bf16x8 a  = *(const bf16x8*)(ap  + (size_t)kb * 32768);
        bf16x8 b0 = *(const bf16x8*)(bp0 + (size_t)kb * 16384);
        bf16x8 b1 = *(const bf16x8*)(bp1 + (size_t)kb * 16384);
        acc0 = MFMA16(a, b0, acc0);
        acc1 = MFMA16(a, b1, acc1);
    }
#pragma unroll
    for (int reg = 0; reg < 4; ++reg) {
        int r = row0 + quad * 4 + reg;
        int c0 = col0 + l16, c1 = col0 + 16 + l16;
        E[(size_t)r * 512 + c0] = fmaxf(acc0[reg] + bias[c0], 0.f);
        E[(size_t)r * 512 + c1] = fmaxf(acc1[reg] + bias[c1], 0.f);
    }
}

// ---------------- persistent LSTM: all 64 steps in one dispatch ----------------
// R4 structure + XCD-LOCAL h-exchange. Analysis (R10): per step each block
// reads 128 KB of hs -> 32 MB/step served from MALL (sc1 stores bypass L2) =
// the dominant ~3-4 us of the 5.7 us step. Fix: rg := PHYSICAL XCD id
// (s_getreg XCC_ID; 116 KB LDS -> exactly 1 block/CU -> exactly 32 blocks/XCD,
// jblk self-assigned via per-XCD atomic slot). Producer and consumers of any
// hs row-range then share an XCD by construction, so hs stores become PLAIN
// (write-through L1 -> dirty in local L2) and consumers' plain loads hit local
// L2 (L1 staleness impossible: each hs address is touched once per CU). Flag
// handshake stays agent-scope sc1 via MALL (ordering: vmcnt(0) drains data to
// L2 before the flag store; flag visibility implies data readable in L2).
__global__ __launch_bounds__(512, 2) void lstm_persist(
        const unsigned short* __restrict__ xbf,   // [T,8,1024,16] bf16 panel-major
        const unsigned short* __restrict__ wt,    // [2048,640] bf16 (n = g*512+j)
        const float* __restrict__ cbias,          // [2048] gate-major
        const float* __restrict__ eimg,           // [B,512]
        unsigned short* __restrict__ hs,          // [T,32,1024,16] bf16 panel-major
        unsigned int* __restrict__ ctr) {         // flags [8][64] + slots [8] at +512
    extern __shared__ unsigned char smem[];
    unsigned short* w_s = (unsigned short*)smem;                    // [64][648] = 82944 B
    float* xbuf = (float*)(smem + 82944);                           // [4][8][64][4] = 32 KB
    unsigned short* scr = (unsigned short*)(smem + 82944 + 32768);  // [4][32][16] = 4 KB
    __shared__ int slot_s;
    const int tid = threadIdx.x;
    const int wave = tid >> 6, lane = tid & 63;
    const int l31 = lane & 31, lh = lane >> 5, h8 = lh * 8;
    const int rt = wave & 3, ks = wave >> 2;

    // self-assign (rg, jblk): rg = physical XCD, jblk = arrival slot on it
    unsigned int xcc;
    asm volatile("s_getreg_b32 %0, hwreg(HW_REG_XCC_ID)" : "=s"(xcc));
    if (tid == 0) {
        unsigned int s = __hip_atomic_fetch_add(ctr + 512 + xcc, 1u,
                                                __ATOMIC_RELAXED, __HIP_MEMORY_SCOPE_AGENT);
        slot_s = (int)s;
    }
    __syncthreads();
    const int rg = (int)xcc;
    const int jblk = slot_s;
    const int j0 = jblk * 16;
    const int rowbase = rg * 128 + rt * 32;
    unsigned int* flags = ctr + rg * 64;

    // stage the block's weight slice: 64 rows (cc = g*16+j) x 640 k, stride 648
    for (int e = tid; e < 64 * 80; e += 512) {
        int r = e / 80, c8 = (e - r * 80) * 8;
        int g = r >> 4, rr = r & 15;
        *(bf16x8*)(w_s + r * 648 + c8) =
            *(const bf16x8*)(wt + (size_t)(g * 512 + j0 + rr) * 640 + c8);
    }
    // per-lane bias vectors: cell j = qq*8 + lh*4 + jj
    f32x4 cbi[2], cbf_[2], cbg[2], cbo[2];
#pragma unroll
    for (int qq = 0; qq < 2; ++qq) {
        cbi[qq]  = *(const f32x4*)(cbias +        j0 + qq * 8 + lh * 4);
        cbf_[qq] = *(const f32x4*)(cbias +  512 + j0 + qq * 8 + lh * 4);
        cbg[qq]  = *(const f32x4*)(cbias + 1024 + j0 + qq * 8 + lh * 4);
        cbo[qq]  = *(const f32x4*)(cbias + 1536 + j0 + qq * 8 + lh * 4);
    }
    __syncthreads();

    float cst[8];
    f32x16 acc0 = ZERO16, acc1 = ZERO16;

    // x-part for t=0 (this wave's K-half)
    {
        const unsigned short* xp = xbf + (size_t)(ks * 4) * 16384
                                       + (size_t)(rowbase + l31) * 16 + h8;
        bf16x8 xreg[4];
#pragma unroll
        for (int kk = 0; kk < 4; ++kk) xreg[kk] = *(const bf16x8*)(xp + kk * 16384);
        __builtin_amdgcn_sched_barrier(0);
        const unsigned short* wx = w_s + (size_t)l31 * 648 + ks * 64 + h8;
#pragma unroll
        for (int kk = 0; kk < 4; ++kk) {
            bf16x8 a0 = *(const bf16x8*)(wx + kk * 16);
            bf16x8 a1 = *(const bf16x8*)(wx + 32 * 648 + kk * 16);
            acc0 = MFMA32(a0, xreg[kk], acc0);
            acc1 = MFMA32(a1, xreg[kk], acc1);
        }
    }

#pragma unroll 1
    for (int t = 0; t < T_; ++t) {
        if (t > 0) {
            // drain prior-step store into local L2 before flagging
            asm volatile("s_waitcnt vmcnt(0)" ::: "memory");
            __syncthreads();                      // A
            if (tid == 0)
                __hip_atomic_store(flags + jblk, (unsigned int)t,
                                   __ATOMIC_RELAXED, __HIP_MEMORY_SCOPE_AGENT);
            if (wave == 0) {
                int guard = 0;
                for (;;) {
                    unsigned int v = __hip_atomic_load(flags + l31,
                                                       __ATOMIC_RELAXED, __HIP_MEMORY_SCOPE_AGENT);
                    if (__all((int)(v >= (unsigned int)t)) || ++guard > (1 << 20)) break;
                }
            }
            __syncthreads();                      // B
            // h B-fragments: 16 contiguous 1 KB panel reads from LOCAL L2
            const unsigned short* hp = hs + (size_t)(t - 1) * (B_ * H_)
                                          + (size_t)(ks * 16) * 16384
                                          + (size_t)(rowbase + l31) * 16 + h8;
            bf16x8 breg[16];
#pragma unroll
            for (int kk = 0; kk < 16; ++kk) breg[kk] = *(const bf16x8*)(hp + (size_t)kk * 16384);
            __builtin_amdgcn_sched_barrier(0);
            const unsigned short* wh = w_s + (size_t)l31 * 648 + 128 + ks * 256 + h8;
#pragma unroll
            for (int kk = 0; kk < 16; ++kk) {
                bf16x8 a0 = *(const bf16x8*)(wh + kk * 16);
                bf16x8 a1 = *(const bf16x8*)(wh + 32 * 648 + kk * 16);
                acc0 = MFMA32(a0, breg[kk], acc0);
                acc1 = MFMA32(a1, breg[kk], acc1);
            }
        }
        // ---- K-split exchange: ks=1 writes partials, ks=0 sums ----
        if (ks == 1) {
            float* xb = xbuf + rt * 2048 + lane * 4;
#pragma unroll
            for (int q = 0; q < 4; ++q)
                *(f32x4*)(xb + q * 256) =
                    (f32x4){acc0[q*4], acc0[q*4+1], acc0[q*4+2], acc0[q*4+3]};
#pragma unroll
            for (int q = 0; q < 4; ++q)
                *(f32x4*)(xb + (4 + q) * 256) =
                    (f32x4){acc1[q*4], acc1[q*4+1], acc1[q*4+2], acc1[q*4+3]};
        }
        __syncthreads();                          // C
        if (ks == 0) {
            const float* xb = xbuf + rt * 2048 + lane * 4;
#pragma unroll
            for (int q = 0; q < 4; ++q) {
                f32x4 p = *(const f32x4*)(xb + q * 256);
                acc0[q*4] += p[0]; acc0[q*4+1] += p[1]; acc0[q*4+2] += p[2]; acc0[q*4+3] += p[3];
            }
#pragma unroll
            for (int q = 0; q < 4; ++q) {
                f32x4 p = *(const f32x4*)(xb + (4 + q) * 256);
                acc1[q*4] += p[0]; acc1[q*4+1] += p[1]; acc1[q*4+2] += p[2]; acc1[q*4+3] += p[3];
            }
            // epilogue: lane owns row r = rowbase+l31, j = qq*8+lh*4+jj;
            // i = acc0[ci], f = acc0[8+ci], g = acc1[ci], o = acc1[8+ci]
            unsigned short* sw = scr + rt * 512 + l31 * 16;
#pragma unroll
            for (int qq = 0; qq < 2; ++qq) {
                f32x4 ea4 = (f32x4){0.f, 0.f, 0.f, 0.f};
                if (t == 0)
                    ea4 = *(const f32x4*)(eimg + (size_t)(rowbase + l31) * 512
                                               + j0 + qq * 8 + lh * 4);
                bf16x4 hv;
#pragma unroll
                for (int jj = 0; jj < 4; ++jj) {
                    int ci = qq * 4 + jj;
                    float iv = sigm(acc0[ci]     + cbi[qq][jj]  + ea4[jj]);
                    float fv = sigm(acc0[8 + ci] + cbf_[qq][jj] + ea4[jj]);
                    float gv = tanh_fast(acc1[ci] + cbg[qq][jj] + ea4[jj]);
                    float ov = sigm(acc1[8 + ci] + cbo[qq][jj] + ea4[jj]);
                    float co = (t == 0) ? 0.f : cst[ci];
                    float cn = fv * co + iv * gv;
                    cst[ci] = cn;
                    hv[jj] = (short)f2bf(ov * tanh_fast(cn));
                }
                *(bf16x4*)(sw + qq * 8 + lh * 4) = hv;
            }
            asm volatile("s_waitcnt lgkmcnt(0)" ::: "memory");
            int4v v = *(const int4v*)(scr + rt * 512 + lane * 8);
            unsigned short* gp = hs + (size_t)t * (B_ * H_) + (size_t)jblk * 16384
                                    + (size_t)(rowbase + (lane >> 1)) * 16 + (lane & 1) * 8;
            *(int4v*)gp = v;                      // PLAIN store -> local L2 (XCD-local consumers)
        }
        if (t < T_ - 1) {
            // pre-compute x-part(t+1) while stores drain / flags propagate
            acc0 = ZERO16; acc1 = ZERO16;
            const unsigned short* xp = xbf + (size_t)(t + 1) * 131072
                                           + (size_t)(ks * 4) * 16384
                                           + (size_t)(rowbase + l31) * 16 + h8;
            bf16x8 xreg[4];
#pragma unroll
            for (int kk = 0; kk < 4; ++kk) xreg[kk] = *(const bf16x8*)(xp + kk * 16384);
            __builtin_amdgcn_sched_barrier(0);
            const unsigned short* wx = w_s + (size_t)l31 * 648 + ks * 64 + h8;
#pragma unroll
            for (int kk = 0; kk < 4; ++kk) {
                bf16x8 a0 = *(const bf16x8*)(wx + kk * 16);
                bf16x8 a1 = *(const bf16x8*)(wx + 32 * 648 + kk * 16);
                acc0 = MFMA32(a0, xreg[kk], acc0);
                acc1 = MFMA32(a1, xreg[kk], acc1);
            }
        }
    }
}

// ---------------- logits + log_softmax via MFMA ----------------
__global__ __launch_bounds__(256, 2) void logits_mfma(
        const unsigned short* __restrict__ hs,    // [T,32,1024,16] bf16 panel-major
        const unsigned short* __restrict__ wo,    // [128][512] bf16, k-major
        const float* __restrict__ ob,             // [128]
        float* __restrict__ out) {                // [65536,128]
    __shared__ unsigned short wos[128 * 264];
    const int tid = threadIdx.x;
    const int wave = tid >> 6, lane = tid & 63;
    const int quad = lane >> 4, l16 = lane & 15;
    const int row0 = blockIdx.x * 64 + wave * 16;
    const int trow = row0 >> 10;                  // all 16 rows of this wave share t
    const int b0 = row0 & 1023;
    const unsigned short* hbase = hs + (size_t)trow * (B_ * H_)
                                     + (size_t)(b0 + l16) * 16 + (quad & 1) * 8;
    f32x4 acc[8];
#pragma unroll
    for (int q = 0; q < 8; ++q) acc[q] = (f32x4){0.f, 0.f, 0.f, 0.f};

    for (int half = 0; half < 2; ++half) {
        __syncthreads();
        for (int e = tid; e < 128 * 32; e += 256) {
            int n = e >> 5, c8 = (e & 31) * 8;
            *(bf16x8*)(wos + n * 264 + c8) = *(const bf16x8*)(wo + n * 512 + half * 256 + c8);
        }
        __syncthreads();
#pragma unroll
        for (int ki = 0; ki < 8; ++ki) {
            int p = half * 16 + ki * 2 + (quad >> 1);
            bf16x8 a = *(const bf16x8*)(hbase + (size_t)p * 16384);
#pragma unroll
            for (int tn = 0; tn < 8; ++tn) {
                bf16x8 b = *(const bf16x8*)(wos + (tn * 16 + l16) * 264 + ki * 32 + quad * 8);
                acc[tn] = MFMA16(a, b, acc[tn]);
            }
        }
    }
    float bia[8];
#pragma unroll
    for (int tn = 0; tn < 8; ++tn) bia[tn] = ob[tn * 16 + l16];
#pragma unroll
    for (int reg = 0; reg < 4; ++reg) {
        float v[8];
        float m = -3.4e38f;
#pragma unroll
        for (int tn = 0; tn < 8; ++tn) { v[tn] = acc[tn][reg] + bia[tn]; m = fmaxf(m, v[tn]); }
#pragma unroll
        for (int off = 1; off < 16; off <<= 1) m = fmaxf(m, __shfl_xor(m, off, 64));
        float s = 0.f;
#pragma unroll
        for (int tn = 0; tn < 8; ++tn) s += __expf(v[tn] - m);
#pragma unroll
        for (int off = 1; off < 16; off <<= 1) s += __shfl_xor(s, off, 64);
        float z = m + __logf(s);
        int row = row0 + quad * 4 + reg;
        float* op = out + (size_t)row * 128;
#pragma unroll
        for (int tn = 0; tn < 8; ++tn) op[tn * 16 + l16] = v[tn] - z;
    }
}

extern "C" void kernel_launch(void* const* d_in, const int* in_sizes, int n_in,
                              void* d_out, int out_size, void* d_ws, size_t ws_size,
                              hipStream_t stream) {
    const float* inp     = (const float*)d_in[0];
    const float* img     = (const float*)d_in[1];
    const float* conv1_w = (const float*)d_in[2];
    const float* conv1_b = (const float*)d_in[3];
    const float* conv2_w = (const float*)d_in[4];
    const float* conv2_b = (const float*)d_in[5];
    const float* imgfc_w = (const float*)d_in[6];
    const float* imgfc_b = (const float*)d_in[7];
    const float* xh_w    = (const float*)d_in[8];
    const float* xh_b    = (const float*)d_in[9];
    const float* hh_w    = (const float*)d_in[10];
    const float* hh_b    = (const float*)d_in[11];
    const float* out_w   = (const float*)d_in[12];
    const float* out_b   = (const float*)d_in[13];

    // ws layout (~88 MB). conv1out/feat2/wfc2 alias the hs region (all dead
    // before lstm_persist writes the overlapping hs[t] slices).
    char* ws = (char*)d_ws;
    unsigned short* hs  = (unsigned short*)(ws);                   // [0,64M): panel-major bf16
    float* conv1out     = (float*)(ws);                            // [0,32M) alias
    unsigned short* feat= (unsigned short*)(ws + (32u << 20));     // [32,39.1M) alias, [113][1024][32]
    unsigned short* wfc = (unsigned short*)(ws + (48u << 20));     // [48,51.6M) alias, [113][512][32]
    float* e            = (float*)(ws + (64u << 20));              // 2 MB
    float* cbias        = (float*)(ws + (66u << 20));              // 8 KB [2048] gate-major
    unsigned short* xbf = (unsigned short*)(ws + (67u << 20));     // 16 MB panel-major
    unsigned short* wt  = (unsigned short*)(ws + (83u << 20));     // 2.56 MB
    unsigned short* wo  = (unsigned short*)(ws + (86u << 20));     // 128 KB
    unsigned int*  ctr  = (unsigned int*)(ws + (87u << 20));       // flags [8][64] + slots [8]
    float* outp         = (float*)d_out;

    prep_k<<<5384, 256, 0, stream>>>(xh_w, hh_w, wt, out_w, wo, xh_b, hh_b, cbias, ctr);
    convx_k<<<(T_ * B_ * 8) / 256, 256, 0, stream>>>(inp, xbf);
    convfw_k<<<226, 256, 0, stream>>>(imgfc_w, wfc);
    conv1_k<<<(B_ * 32 * 32) / 256, 256, 0, stream>>>(img, conv1_w, conv1_b, conv1out);
    conv2_k<<<B_, 256, 0, stream>>>(conv1out, conv2_w, conv2_b, feat);
    imgfc_mfma<<<dim3(16, 16), 256, 0, stream>>>(feat, wfc, imgfc_b, e);

    lstm_persist<<<256, 512, 82944 + 32768 + 4096, stream>>>(
        xbf, wt, cbias, e, hs, ctr);

    logits_mfma<<<(T_ * B_) / 64, 256, 0, stream>>>(hs, wo, out_b, outp);
}

// Round 12
// 725.606 us; speedup vs baseline: 1.6535x; 1.6535x over previous
//
#include <hip/hip_runtime.h>

// Model dims
#define T_ 64
#define B_ 1024
#define V_ 128
#define H_ 512
#define KFC 3616   // imgfc K padded (3600 + 16 zeros); 113 k-blocks of 32

typedef short bf16x8 __attribute__((ext_vector_type(8)));
typedef short bf16x4 __attribute__((ext_vector_type(4)));
typedef float f32x4 __attribute__((ext_vector_type(4)));
typedef float f32x16 __attribute__((ext_vector_type(16)));
typedef int int4v __attribute__((ext_vector_type(4)));

#define ZERO16 ((f32x16){0.f,0.f,0.f,0.f,0.f,0.f,0.f,0.f,0.f,0.f,0.f,0.f,0.f,0.f,0.f,0.f})

__device__ __forceinline__ unsigned short f2bf(float f) {
    union { float f; unsigned int i; } v; v.f = f;
    unsigned int x = v.i;
    return (unsigned short)((x + 0x7FFFu + ((x >> 16) & 1u)) >> 16);
}
__device__ __forceinline__ float sigm(float x) { return 1.f / (1.f + __expf(-x)); }
__device__ __forceinline__ float tanh_fast(float x) {
    float ax = fabsf(x);
    float t = 1.f - 2.f / (__expf(2.f * ax) + 1.f);   // saturates to 1 on overflow
    return copysignf(t, x);
}

// ---------------- fused prep (184 blocks, all coalesced via LDS tiles) ----------------
// bx 0..159  : wt [2048][640] bf16 transpose of {xh_w[128][2048], hh_w[512][2048]}
// bx 160..175: wo [128][512] bf16 transpose of out_w [512][128]
// bx 176..183: cbias = xh_b + hh_b; zero flags/slots
// (R10's prep read xw at 8KB lane stride - 1 elem per 64B line, 5120 blocks,
//  latency-bound. LDS 32x256 tile transpose like convfw_k fixes it.)
__global__ __launch_bounds__(256) void prep_k(const float* __restrict__ xw,
                                              const float* __restrict__ hw,
                                              unsigned short* __restrict__ wt,
                                              const float* __restrict__ ow,
                                              unsigned short* __restrict__ wo,
                                              const float* __restrict__ xh_b,
                                              const float* __restrict__ hh_b,
                                              float* __restrict__ cbias,
                                              unsigned int* __restrict__ ctr) {
    __shared__ float ts[32][257];
    int bx = blockIdx.x, tid = threadIdx.x;
    if (bx < 160) {
        int k0 = (bx >> 3) * 32, n0 = (bx & 7) * 256;   // k0 in wt-space 0..608
#pragma unroll
        for (int r = 0; r < 32; ++r) {
            int k = k0 + r;
            ts[r][tid] = (k < 128) ? xw[(size_t)k * 2048 + n0 + tid]
                                   : hw[(size_t)(k - 128) * 2048 + n0 + tid];
        }
        __syncthreads();
        unsigned short* op = wt + (size_t)(n0 + tid) * 640 + k0;
#pragma unroll
        for (int m = 0; m < 4; ++m) {
            bf16x8 o;
#pragma unroll
            for (int e = 0; e < 8; ++e) o[e] = (short)f2bf(ts[m * 8 + e][tid]);
            *(bf16x8*)(op + m * 8) = o;
        }
    } else if (bx < 176) {
        int k0 = (bx - 160) * 32;                       // 16 tiles cover k 0..511
        if (tid < 128) {
#pragma unroll
            for (int r = 0; r < 32; ++r)
                ts[r][tid] = ow[(size_t)(k0 + r) * 128 + tid];
        }
        __syncthreads();
        if (tid < 128) {
            unsigned short* op = wo + (size_t)tid * 512 + k0;
#pragma unroll
            for (int m = 0; m < 4; ++m) {
                bf16x8 o;
#pragma unroll
                for (int e = 0; e < 8; ++e) o[e] = (short)f2bf(ts[m * 8 + e][tid]);
                *(bf16x8*)(op + m * 8) = o;
            }
        }
    } else {
        int i = (bx - 176) * 256 + tid;                 // 2048
        cbias[i] = xh_b[i] + hh_b[i];
        if (i < 576) ctr[i] = 0u;                       // flags[8][64] (+ spare)
    }
}

// ---------------- convert inp fp32 -> bf16, PANEL-MAJOR [T][8][1024][16] ----------------
__global__ __launch_bounds__(256) void convx_k(const float* __restrict__ x,
                                               unsigned short* __restrict__ xbf) {
    int e = blockIdx.x * 256 + threadIdx.x;          // T*B*8 = 524288
    int t = e >> 13, r = e & 8191;
    int panel = r >> 10, b = r & 1023;
    const float* ip = x + ((size_t)t * 1024 + b) * 128 + panel * 16;
    unsigned short* op = xbf + (size_t)t * 131072 + panel * 16384 + b * 16;
#pragma unroll
    for (int h = 0; h < 2; ++h) {
        float4 f0 = *(const float4*)(ip + h * 8);
        float4 f1 = *(const float4*)(ip + h * 8 + 4);
        bf16x8 o;
        o[0] = (short)f2bf(f0.x); o[1] = (short)f2bf(f0.y);
        o[2] = (short)f2bf(f0.z); o[3] = (short)f2bf(f0.w);
        o[4] = (short)f2bf(f1.x); o[5] = (short)f2bf(f1.y);
        o[6] = (short)f2bf(f1.z); o[7] = (short)f2bf(f1.w);
        *(bf16x8*)(op + h * 8) = o;
    }
}

// ---------------- imgfc_w [3600][512] f32 -> wfc2 TILE-MAJOR [113][512][32] bf16 ----------------
__global__ __launch_bounds__(256) void convfw_k(const float* __restrict__ w,
                                                unsigned short* __restrict__ wn) {
    __shared__ float ts[32][257];
    int bx = blockIdx.x;                              // 226 = 113 kb x 2 n-halves
    int kb = bx >> 1, n0 = (bx & 1) * 256;
    int tid = threadIdx.x;
#pragma unroll
    for (int r = 0; r < 32; ++r) {
        int k = kb * 32 + r;
        ts[r][tid] = (k < 3600) ? w[(size_t)k * 512 + n0 + tid] : 0.f;
    }
    __syncthreads();
    unsigned short* op = wn + (size_t)kb * 16384 + (size_t)(n0 + tid) * 32;
#pragma unroll
    for (int m = 0; m < 4; ++m) {
        bf16x8 o;
#pragma unroll
        for (int e = 0; e < 8; ++e) o[e] = (short)f2bf(ts[m * 8 + e][tid]);
        *(bf16x8*)(op + m * 8) = o;
    }
}

// ---------------- conv1 3x3 pad1 + relu + 2x2 maxpool ----------------
__global__ __launch_bounds__(256) void conv1_k(const float* __restrict__ img,
                                               const float* __restrict__ w,
                                               const float* __restrict__ bias,
                                               float* __restrict__ out) {
    int id = blockIdx.x * 256 + threadIdx.x;         // B*32*32 = 1048576
    int px = id & 31, py = (id >> 5) & 31, b = id >> 10;
    const float* ip = img + b * 4096;
    float in4[4][4];
#pragma unroll
    for (int dy = 0; dy < 4; ++dy) {
        int iy = 2 * py + dy - 1;
#pragma unroll
        for (int dx = 0; dx < 4; ++dx) {
            int ix = 2 * px + dx - 1;
            in4[dy][dx] = (iy >= 0 && iy < 64 && ix >= 0 && ix < 64) ? ip[iy * 64 + ix] : 0.f;
        }
    }
    float* op = out + b * 8192 + py * 32 + px;
#pragma unroll
    for (int oc = 0; oc < 8; ++oc) {
        float wv[9];
#pragma unroll
        for (int t = 0; t < 9; ++t) wv[t] = w[oc * 9 + t];
        float bs = bias[oc];
        float m = -3.4e38f;
#pragma unroll
        for (int sy = 0; sy < 2; ++sy)
#pragma unroll
        for (int sx = 0; sx < 2; ++sx) {
            float acc = bs;
#pragma unroll
            for (int ky = 0; ky < 3; ++ky)
#pragma unroll
            for (int kx = 0; kx < 3; ++kx)
                acc += in4[sy + ky][sx + kx] * wv[ky * 3 + kx];
            m = fmaxf(m, acc);
        }
        op[oc * 1024] = fmaxf(m, 0.f);
    }
}

// ---------------- conv2 5x5 pad1 + relu + 2x2 maxpool -> feat2 TILE-MAJOR [113][1024][32] ----------------
__device__ __forceinline__ int c2idx(int ic, int y, int x) {
    return ((ic * 34 + y) * 2 + (x & 1)) * 18 + (x >> 1);
}
__global__ __launch_bounds__(256) void conv2_k(const float* __restrict__ in,
                                               const float* __restrict__ w,
                                               const float* __restrict__ bias,
                                               unsigned short* __restrict__ feat) {
    __shared__ float in_s[8 * 34 * 36];
    __shared__ float w_s[3200];
    __shared__ float b_s[16];
    int tid = threadIdx.x, b = blockIdx.x;
    for (int e = tid; e < 8 * 34 * 34; e += 256) {
        int ic = e / 1156, r = e - ic * 1156;
        int y = r / 34, xx = r - y * 34;
        float v = 0.f;
        if (y >= 1 && y <= 32 && xx >= 1 && xx <= 32)
            v = in[b * 8192 + ic * 1024 + (y - 1) * 32 + (xx - 1)];
        in_s[c2idx(ic, y, xx)] = v;
    }
    for (int e = tid; e < 3200; e += 256) w_s[e] = w[e];
    if (tid < 16) b_s[tid] = bias[tid];
    if (tid < 16) feat[(size_t)112 * 32768 + (size_t)b * 32 + 16 + tid] = 0;  // K tail
    __syncthreads();
    for (int o = tid; o < 3600; o += 256) {
        int oc = o / 225, p = o - oc * 225;
        int py = p / 15, px = p - py * 15;
        int y0 = 2 * py;
        float a00, a01, a10, a11;
        a00 = a01 = a10 = a11 = b_s[oc];
        for (int ic = 0; ic < 8; ++ic) {
            const float* wp = w_s + (oc * 8 + ic) * 25;
            float cur[6], nxt[6];
#pragma unroll
            for (int xx = 0; xx < 6; ++xx) cur[xx] = in_s[c2idx(ic, y0, 2 * px + xx)];
#pragma unroll
            for (int ky = 0; ky < 5; ++ky) {
#pragma unroll
                for (int xx = 0; xx < 6; ++xx) nxt[xx] = in_s[c2idx(ic, y0 + ky + 1, 2 * px + xx)];
#pragma unroll
                for (int kx = 0; kx < 5; ++kx) {
                    float wv = wp[ky * 5 + kx];
                    a00 += cur[kx    ] * wv;
                    a01 += cur[kx + 1] * wv;
                    a10 += nxt[kx    ] * wv;
                    a11 += nxt[kx + 1] * wv;
                }
#pragma unroll
                for (int xx = 0; xx < 6; ++xx) cur[xx] = nxt[xx];
            }
        }
        float mx = fmaxf(fmaxf(a00, a01), fmaxf(a10, a11));
        feat[(size_t)(o >> 5) * 32768 + (size_t)b * 32 + (o & 31)] = f2bf(fmaxf(mx, 0.f));
    }
}

#define MFMA16(a, b, c) __builtin_amdgcn_mfma_f32_16x16x32_bf16((a), (b), (c), 0, 0, 0)
#define MFMA32(a, b, c) __builtin_amdgcn_mfma_f32_32x32x16_bf16((a), (b), (c), 0, 0, 0)

// ---------------- imgfc via MFMA: e = relu(feat @ W + b), tile-major operands ----------------
__global__ __launch_bounds__(256) void imgfc_mfma(const unsigned short* __restrict__ A2,
                                                  const unsigned short* __restrict__ W2,
                                                  const float* __restrict__ bias,
                                                  float* __restrict__ E) {
    const int tid = threadIdx.x;
    const int wv = tid >> 6, lane = tid & 63;
    const int quad = lane >> 4, l16 = lane & 15;
    const int row0 = blockIdx.x * 64 + wv * 16;
    const int col0 = blockIdx.y * 32;
    const unsigned short* ap = A2 + (size_t)(row0 + l16) * 32 + quad * 8;
    const unsigned short* bp0 = W2 + (size_t)(col0 + l16) * 32 + quad * 8;
    const unsigned short* bp1 = W2 + (size_t)(col0 + 16 + l16) * 32 + quad * 8;
    f32x4 acc0 = (f32x4){0.f, 0.f, 0.f, 0.f};
    f32x4 acc1 = (f32x4){0.f, 0.f, 0.f, 0.f};
#pragma unroll 4
    for (int kb = 0; kb < 113; ++kb) {
        bf16x8 a  = *(const bf16x8*)(ap  + (size_t)kb * 32768);
        bf16x8 b0 = *(const bf16x8*)(bp0 + (size_t)kb * 16384);
        bf16x8 b1 = *(const bf16x8*)(bp1 + (size_t)kb * 16384);
        acc0 = MFMA16(a, b0, acc0);
        acc1 = MFMA16(a, b1, acc1);
    }
#pragma unroll
    for (int reg = 0; reg < 4; ++reg) {
        int r = row0 + quad * 4 + reg;
        int c0 = col0 + l16, c1 = col0 + 16 + l16;
        E[(size_t)r * 512 + c0] = fmaxf(acc0[reg] + bias[c0], 0.f);
        E[(size_t)r * 512 + c1] = fmaxf(acc1[reg] + bias[c1], 0.f);
    }
}

// ---------------- persistent LSTM: all 64 steps in one dispatch ----------------
// R10-exact (365 us, verified x3). 256 blocks x 512 threads (8 waves).
// Block = (rg = blockIdx&7, jblk = blockIdx>>3). Wave = (rt, ks): 32 batch x
// 64 gate-cols x K-half, 32x32x16 MFMA, operand swap. K-split via LDS xbuf;
// ks=0 epilogue; full-line 512 B sc0sc1 stores via scr repack; wave0 poll.
// R11 LESSON: plain write-back hs stores regressed 2.3x - L2 write-allocate
// RFO fetches every hs line from MALL under the vmcnt drain (FETCH unchanged
// because RFO hits MALL, not HBM). Keep sc0 sc1 write-through. Do not retry.
__global__ __launch_bounds__(512, 2) void lstm_persist(
        const unsigned short* __restrict__ xbf,   // [T,8,1024,16] bf16 panel-major
        const unsigned short* __restrict__ wt,    // [2048,640] bf16 (n = g*512+j)
        const float* __restrict__ cbias,          // [2048] gate-major
        const float* __restrict__ eimg,           // [B,512]
        unsigned short* __restrict__ hs,          // [T,32,1024,16] bf16 panel-major
        unsigned int* __restrict__ ctr) {         // flags [8][64]
    extern __shared__ unsigned char smem[];
    unsigned short* w_s = (unsigned short*)smem;                    // [64][648] = 82944 B
    float* xbuf = (float*)(smem + 82944);                           // [4][8][64][4] = 32 KB
    unsigned short* scr = (unsigned short*)(smem + 82944 + 32768);  // [4][32][16] = 4 KB
    const int tid = threadIdx.x;
    const int wave = tid >> 6, lane = tid & 63;
    const int l31 = lane & 31, lh = lane >> 5, h8 = lh * 8;
    const int rt = wave & 3, ks = wave >> 2;
    const int rg = blockIdx.x & 7;                // XCD swizzle
    const int jblk = blockIdx.x >> 3;
    const int j0 = jblk * 16;
    const int rowbase = rg * 128 + rt * 32;
    unsigned int* flags = ctr + rg * 64;

    // stage the block's weight slice: 64 rows (cc = g*16+j) x 640 k, stride 648
    for (int e = tid; e < 64 * 80; e += 512) {
        int r = e / 80, c8 = (e - r * 80) * 8;
        int g = r >> 4, rr = r & 15;
        *(bf16x8*)(w_s + r * 648 + c8) =
            *(const bf16x8*)(wt + (size_t)(g * 512 + j0 + rr) * 640 + c8);
    }
    // per-lane bias vectors: cell j = qq*8 + lh*4 + jj
    f32x4 cbi[2], cbf_[2], cbg[2], cbo[2];
#pragma unroll
    for (int qq = 0; qq < 2; ++qq) {
        cbi[qq]  = *(const f32x4*)(cbias +        j0 + qq * 8 + lh * 4);
        cbf_[qq] = *(const f32x4*)(cbias +  512 + j0 + qq * 8 + lh * 4);
        cbg[qq]  = *(const f32x4*)(cbias + 1024 + j0 + qq * 8 + lh * 4);
        cbo[qq]  = *(const f32x4*)(cbias + 1536 + j0 + qq * 8 + lh * 4);
    }
    __syncthreads();

    float cst[8];
    f32x16 acc0 = ZERO16, acc1 = ZERO16;

    // x-part for t=0 (this wave's K-half)
    {
        const unsigned short* xp = xbf + (size_t)(ks * 4) * 16384
                                       + (size_t)(rowbase + l31) * 16 + h8;
        bf16x8 xreg[4];
#pragma unroll
        for (int kk = 0; kk < 4; ++kk) xreg[kk] = *(const bf16x8*)(xp + kk * 16384);
        __builtin_amdgcn_sched_barrier(0);
        const unsigned short* wx = w_s + (size_t)l31 * 648 + ks * 64 + h8;
#pragma unroll
        for (int kk = 0; kk < 4; ++kk) {
            bf16x8 a0 = *(const bf16x8*)(wx + kk * 16);
            bf16x8 a1 = *(const bf16x8*)(wx + 32 * 648 + kk * 16);
            acc0 = MFMA32(a0, xreg[kk], acc0);
            acc1 = MFMA32(a1, xreg[kk], acc1);
        }
    }

#pragma unroll 1
    for (int t = 0; t < T_; ++t) {
        if (t > 0) {
            // drain prior-step sc1 store (inline-asm store invisible to compiler)
            asm volatile("s_waitcnt vmcnt(0)" ::: "memory");
            __syncthreads();                      // A
            if (tid == 0)
                __hip_atomic_store(flags + jblk, (unsigned int)t,
                                   __ATOMIC_RELAXED, __HIP_MEMORY_SCOPE_AGENT);
            if (wave == 0) {
                int guard = 0;
                for (;;) {
                    unsigned int v = __hip_atomic_load(flags + l31,
                                                       __ATOMIC_RELAXED, __HIP_MEMORY_SCOPE_AGENT);
                    if (__all((int)(v >= (unsigned int)t)) || ++guard > (1 << 20)) break;
                }
            }
            __syncthreads();                      // B
            // h B-fragments: 16 contiguous 1 KB panel reads, prefetched+pinned
            const unsigned short* hp = hs + (size_t)(t - 1) * (B_ * H_)
                                          + (size_t)(ks * 16) * 16384
                                          + (size_t)(rowbase + l31) * 16 + h8;
            bf16x8 breg[16];
#pragma unroll
            for (int kk = 0; kk < 16; ++kk) breg[kk] = *(const bf16x8*)(hp + (size_t)kk * 16384);
            __builtin_amdgcn_sched_barrier(0);
            const unsigned short* wh = w_s + (size_t)l31 * 648 + 128 + ks * 256 + h8;
#pragma unroll
            for (int kk = 0; kk < 16; ++kk) {
                bf16x8 a0 = *(const bf16x8*)(wh + kk * 16);
                bf16x8 a1 = *(const bf16x8*)(wh + 32 * 648 + kk * 16);
                acc0 = MFMA32(a0, breg[kk], acc0);
                acc1 = MFMA32(a1, breg[kk], acc1);
            }
        }
        // ---- K-split exchange: ks=1 writes partials, ks=0 sums ----
        if (ks == 1) {
            float* xb = xbuf + rt * 2048 + lane * 4;
#pragma unroll
            for (int q = 0; q < 4; ++q)
                *(f32x4*)(xb + q * 256) =
                    (f32x4){acc0[q*4], acc0[q*4+1], acc0[q*4+2], acc0[q*4+3]};
#pragma unroll
            for (int q = 0; q < 4; ++q)
                *(f32x4*)(xb + (4 + q) * 256) =
                    (f32x4){acc1[q*4], acc1[q*4+1], acc1[q*4+2], acc1[q*4+3]};
        }
        __syncthreads();                          // C
        if (ks == 0) {
            const float* xb = xbuf + rt * 2048 + lane * 4;
#pragma unroll
            for (int q = 0; q < 4; ++q) {
                f32x4 p = *(const f32x4*)(xb + q * 256);
                acc0[q*4] += p[0]; acc0[q*4+1] += p[1]; acc0[q*4+2] += p[2]; acc0[q*4+3] += p[3];
            }
#pragma unroll
            for (int q = 0; q < 4; ++q) {
                f32x4 p = *(const f32x4*)(xb + (4 + q) * 256);
                acc1[q*4] += p[0]; acc1[q*4+1] += p[1]; acc1[q*4+2] += p[2]; acc1[q*4+3] += p[3];
            }
            // epilogue: lane owns row r = rowbase+l31, j = qq*8+lh*4+jj;
            // i = acc0[ci], f = acc0[8+ci], g = acc1[ci], o = acc1[8+ci]
            unsigned short* sw = scr + rt * 512 + l31 * 16;
#pragma unroll
            for (int qq = 0; qq < 2; ++qq) {
                f32x4 ea4 = (f32x4){0.f, 0.f, 0.f, 0.f};
                if (t == 0)
                    ea4 = *(const f32x4*)(eimg + (size_t)(rowbase + l31) * 512
                                               + j0 + qq * 8 + lh * 4);
                bf16x4 hv;
#pragma unroll
                for (int jj = 0; jj < 4; ++jj) {
                    int ci = qq * 4 + jj;
                    float iv = sigm(acc0[ci]     + cbi[qq][jj]  + ea4[jj]);
                    float fv = sigm(acc0[8 + ci] + cbf_[qq][jj] + ea4[jj]);
                    float gv = tanh_fast(acc1[ci] + cbg[qq][jj] + ea4[jj]);
                    float ov = sigm(acc1[8 + ci] + cbo[qq][jj] + ea4[jj]);
                    float co = (t == 0) ? 0.f : cst[ci];
                    float cn = fv * co + iv * gv;
                    cst[ci] = cn;
                    hv[jj] = (short)f2bf(ov * tanh_fast(cn));
                }
                *(bf16x4*)(sw + qq * 8 + lh * 4) = hv;
            }
            asm volatile("s_waitcnt lgkmcnt(0)" ::: "memory");
            int4v v = *(const int4v*)(scr + rt * 512 + lane * 8);
            unsigned short* gp = hs + (size_t)t * (B_ * H_) + (size_t)jblk * 16384
                                    + (size_t)(rowbase + (lane >> 1)) * 16 + (lane & 1) * 8;
            asm volatile("global_store_dwordx4 %0, %1, off sc0 sc1" :: "v"(gp), "v"(v) : "memory");
        }
        if (t < T_ - 1) {
            // pre-compute x-part(t+1) while stores drain / flags propagate
            acc0 = ZERO16; acc1 = ZERO16;
            const unsigned short* xp = xbf + (size_t)(t + 1) * 131072
                                           + (size_t)(ks * 4) * 16384
                                           + (size_t)(rowbase + l31) * 16 + h8;
            bf16x8 xreg[4];
#pragma unroll
            for (int kk = 0; kk < 4; ++kk) xreg[kk] = *(const bf16x8*)(xp + kk * 16384);
            __builtin_amdgcn_sched_barrier(0);
            const unsigned short* wx = w_s + (size_t)l31 * 648 + ks * 64 + h8;
#pragma unroll
            for (int kk = 0; kk < 4; ++kk) {
                bf16x8 a0 = *(const bf16x8*)(wx + kk * 16);
                bf16x8 a1 = *(const bf16x8*)(wx + 32 * 648 + kk * 16);
                acc0 = MFMA32(a0, xreg[kk], acc0);
                acc1 = MFMA32(a1, xreg[kk], acc1);
            }
        }
    }
}

// ---------------- logits + log_softmax via MFMA ----------------
__global__ __launch_bounds__(256, 2) void logits_mfma(
        const unsigned short* __restrict__ hs,    // [T,32,1024,16] bf16 panel-major
        const unsigned short* __restrict__ wo,    // [128][512] bf16, k-major
        const float* __restrict__ ob,             // [128]
        float* __restrict__ out) {                // [65536,128]
    __shared__ unsigned short wos[128 * 264];
    const int tid = threadIdx.x;
    const int wave = tid >> 6, lane = tid & 63;
    const int quad = lane >> 4, l16 = lane & 15;
    const int row0 = blockIdx.x * 64 + wave * 16;
    const int trow = row0 >> 10;                  // all 16 rows of this wave share t
    const int b0 = row0 & 1023;
    const unsigned short* hbase = hs + (size_t)trow * (B_ * H_)
                                     + (size_t)(b0 + l16) * 16 + (quad & 1) * 8;
    f32x4 acc[8];
#pragma unroll
    for (int q = 0; q < 8; ++q) acc[q] = (f32x4){0.f, 0.f, 0.f, 0.f};

    for (int half = 0; half < 2; ++half) {
        __syncthreads();
        for (int e = tid; e < 128 * 32; e += 256) {
            int n = e >> 5, c8 = (e & 31) * 8;
            *(bf16x8*)(wos + n * 264 + c8) = *(const bf16x8*)(wo + n * 512 + half * 256 + c8);
        }
        __syncthreads();
#pragma unroll
        for (int ki = 0; ki < 8; ++ki) {
            int p = half * 16 + ki * 2 + (quad >> 1);
            bf16x8 a = *(const bf16x8*)(hbase + (size_t)p * 16384);
#pragma unroll
            for (int tn = 0; tn < 8; ++tn) {
                bf16x8 b = *(const bf16x8*)(wos + (tn * 16 + l16) * 264 + ki * 32 + quad * 8);
                acc[tn] = MFMA16(a, b, acc[tn]);
            }
        }
    }
    float bia[8];
#pragma unroll
    for (int tn = 0; tn < 8; ++tn) bia[tn] = ob[tn * 16 + l16];
#pragma unroll
    for (int reg = 0; reg < 4; ++reg) {
        float v[8];
        float m = -3.4e38f;
#pragma unroll
        for (int tn = 0; tn < 8; ++tn) { v[tn] = acc[tn][reg] + bia[tn]; m = fmaxf(m, v[tn]); }
#pragma unroll
        for (int off = 1; off < 16; off <<= 1) m = fmaxf(m, __shfl_xor(m, off, 64));
        float s = 0.f;
#pragma unroll
        for (int tn = 0; tn < 8; ++tn) s += __expf(v[tn] - m);
#pragma unroll
        for (int off = 1; off < 16; off <<= 1) s += __shfl_xor(s, off, 64);
        float z = m + __logf(s);
        int row = row0 + quad * 4 + reg;
        float* op = out + (size_t)row * 128;
#pragma unroll
        for (int tn = 0; tn < 8; ++tn) op[tn * 16 + l16] = v[tn] - z;
    }
}

extern "C" void kernel_launch(void* const* d_in, const int* in_sizes, int n_in,
                              void* d_out, int out_size, void* d_ws, size_t ws_size,
                              hipStream_t stream) {
    const float* inp     = (const float*)d_in[0];
    const float* img     = (const float*)d_in[1];
    const float* conv1_w = (const float*)d_in[2];
    const float* conv1_b = (const float*)d_in[3];
    const float* conv2_w = (const float*)d_in[4];
    const float* conv2_b = (const float*)d_in[5];
    const float* imgfc_w = (const float*)d_in[6];
    const float* imgfc_b = (const float*)d_in[7];
    const float* xh_w    = (const float*)d_in[8];
    const float* xh_b    = (const float*)d_in[9];
    const float* hh_w    = (const float*)d_in[10];
    const float* hh_b    = (const float*)d_in[11];
    const float* out_w   = (const float*)d_in[12];
    const float* out_b   = (const float*)d_in[13];

    // ws layout (~88 MB). conv1out/feat2/wfc2 alias the hs region (all dead
    // before lstm_persist writes the overlapping hs[t] slices).
    char* ws = (char*)d_ws;
    unsigned short* hs  = (unsigned short*)(ws);                   // [0,64M): panel-major bf16
    float* conv1out     = (float*)(ws);                            // [0,32M) alias
    unsigned short* feat= (unsigned short*)(ws + (32u << 20));     // [32,39.1M) alias, [113][1024][32]
    unsigned short* wfc = (unsigned short*)(ws + (48u << 20));     // [48,51.6M) alias, [113][512][32]
    float* e            = (float*)(ws + (64u << 20));              // 2 MB
    float* cbias        = (float*)(ws + (66u << 20));              // 8 KB [2048] gate-major
    unsigned short* xbf = (unsigned short*)(ws + (67u << 20));     // 16 MB panel-major
    unsigned short* wt  = (unsigned short*)(ws + (83u << 20));     // 2.56 MB
    unsigned short* wo  = (unsigned short*)(ws + (86u << 20));     // 128 KB
    unsigned int*  ctr  = (unsigned int*)(ws + (87u << 20));       // flags [8][64]
    float* outp         = (float*)d_out;

    prep_k<<<184, 256, 0, stream>>>(xh_w, hh_w, wt, out_w, wo, xh_b, hh_b, cbias, ctr);
    convx_k<<<(T_ * B_ * 8) / 256, 256, 0, stream>>>(inp, xbf);
    convfw_k<<<226, 256, 0, stream>>>(imgfc_w, wfc);
    conv1_k<<<(B_ * 32 * 32) / 256, 256, 0, stream>>>(img, conv1_w, conv1_b, conv1out);
    conv2_k<<<B_, 256, 0, stream>>>(conv1out, conv2_w, conv2_b, feat);
    imgfc_mfma<<<dim3(16, 16), 256, 0, stream>>>(feat, wfc, imgfc_b, e);

    lstm_persist<<<256, 512, 82944 + 32768 + 4096, stream>>>(
        xbf, wt, cbias, e, hs, ctr);

    logits_mfma<<<(T_ * B_) / 64, 256, 0, stream>>>(hs, wo, out_b, outp);
}